// Round 3
// baseline (616.607 us; speedup 1.0000x reference)
//
#include <hip/hip_runtime.h>

#define D_MODEL 256
#define NSEQ    8192
#define JG      8          // j-split groups for fused score+PV kernel

typedef _Float16 half8 __attribute__((ext_vector_type(8)));
typedef _Float16 half4 __attribute__((ext_vector_type(4)));
typedef float    f32x4 __attribute__((ext_vector_type(4)));

__device__ __forceinline__ half8 cvt8(f32x4 a, f32x4 b) {
  half8 h;
  h[0]=(_Float16)a[0]; h[1]=(_Float16)a[1]; h[2]=(_Float16)a[2]; h[3]=(_Float16)a[3];
  h[4]=(_Float16)b[0]; h[5]=(_Float16)b[1]; h[6]=(_Float16)b[2]; h[7]=(_Float16)b[3];
  return h;
}

__device__ __forceinline__ half8 load8_f32(const float* p) {
  f32x4 a = *(const f32x4*)p;
  f32x4 b = *(const f32x4*)(p + 4);
  return cvt8(a, b);
}

// ---------------------------------------------------------------------------
// k1: QKV = x @ W^T  (fp32 inputs read direct from L2/L3, cvt to fp16 in regs)
// Q,K -> QK16 [8192 x 512] fp16 (Q cols 0-255, K cols 256-511)
// V   -> VT   [256 x 8192] fp16 (transposed, B-operand for PV)
// MFMA f16 16x16x32. A[m=lane&15][k=quad*8+j]; B^T-gemm B[n=lane&15][k=...];
// C/D: col=lane&15, row=quad*4+reg (HW-verified layouts, guide §3).
// ---------------------------------------------------------------------------
__global__ __launch_bounds__(256) void qkv_kernel(
    const float* __restrict__ x, const float* __restrict__ Wq,
    const float* __restrict__ Wk, const float* __restrict__ Wv,
    _Float16* __restrict__ QK16, _Float16* __restrict__ VT)
{
  const int tid  = threadIdx.x;
  const int lane = tid & 63;
  const int wave = tid >> 6;
  const int c    = lane & 15;
  const int quad = lane >> 4;
  const int M0   = blockIdx.x * 128 + (wave >> 1) * 64;
  const int Nblk = blockIdx.y * 128 + (wave & 1) * 64;   // 0..767
  const int widx = Nblk >> 8;                            // 0=Q,1=K,2=V
  const int nloc = Nblk & 255;
  const float* W = (widx == 0) ? Wq : (widx == 1 ? Wk : Wv);

  f32x4 acc[4][4] = {};
  for (int k0 = 0; k0 < D_MODEL; k0 += 32) {
    half8 af[4], bf[4];
#pragma unroll
    for (int mt = 0; mt < 4; ++mt)
      af[mt] = load8_f32(&x[(size_t)(M0 + mt*16 + c) * D_MODEL + k0 + quad*8]);
#pragma unroll
    for (int nt = 0; nt < 4; ++nt)
      bf[nt] = load8_f32(&W[(size_t)(nloc + nt*16 + c) * D_MODEL + k0 + quad*8]);
#pragma unroll
    for (int mt = 0; mt < 4; ++mt)
#pragma unroll
      for (int nt = 0; nt < 4; ++nt)
        acc[mt][nt] = __builtin_amdgcn_mfma_f32_16x16x32_f16(af[mt], bf[nt], acc[mt][nt], 0, 0, 0);
  }

  if (widx < 2) {
#pragma unroll
    for (int mt = 0; mt < 4; ++mt)
#pragma unroll
      for (int nt = 0; nt < 4; ++nt) {
        const int col  = widx * 256 + nloc + nt*16 + c;
        const int row0 = M0 + mt*16 + quad*4;
#pragma unroll
        for (int r = 0; r < 4; ++r)
          QK16[(size_t)(row0 + r) * 512 + col] = (_Float16)acc[mt][nt][r];
      }
  } else {
#pragma unroll
    for (int mt = 0; mt < 4; ++mt)
#pragma unroll
      for (int nt = 0; nt < 4; ++nt) {
        const int d  = nloc + nt*16 + c;
        const int m0 = M0 + mt*16 + quad*4;
        half4 h;
        h[0]=(_Float16)acc[mt][nt][0]; h[1]=(_Float16)acc[mt][nt][1];
        h[2]=(_Float16)acc[mt][nt][2]; h[3]=(_Float16)acc[mt][nt][3];
        *(half4*)&VT[(size_t)d * NSEQ + m0] = h;
      }
  }
}

// ---------------------------------------------------------------------------
// k2: fused score+PV, NO attn traffic. WG = 4 waves, owns 64 rows x 1/JG of j.
// Per 128-col j-step: wave w computes e^s for cols [j0+32w, j0+32w+32),
// accumulates row sums in regs, stores p fp16 to LDS (C->A layout), then all
// waves MFMA Ps @ VT^T into register cntx accs (wave w owns d-cols [64w,+64)).
// Epilogue: per-row lsum atomics + one atomicAdd per UNNORMALIZED cntx element
// (normalized afterwards by scale_cntx_kernel — R2 bug was missing this).
// ---------------------------------------------------------------------------
#define PSTRIDE 136   // halves; 272B row stride

__global__ __launch_bounds__(256) void fused_pv_kernel(
    const _Float16* __restrict__ QK16, const _Float16* __restrict__ VT,
    float* __restrict__ lsum, float* __restrict__ cntx)
{
  __shared__ _Float16 Ps[64 * PSTRIDE];
  const int tid  = threadIdx.x;
  const int lane = tid & 63;
  const int wave = tid >> 6;
  const int c    = lane & 15;
  const int quad = lane >> 4;
  const int M0   = blockIdx.x * 64;
  const int jb   = blockIdx.y * (NSEQ / JG);
  const int je   = jb + NSEQ / JG;

  f32x4 cacc[4][4] = {};   // cntx acc: rows mt*16+quad*4+r, cols wave*64+nt*16+c
  float psum[4][4] = {};   // row-sum partials: row = mt*16+quad*4+r

  for (int j0 = jb; j0 < je; j0 += 128) {
    // ---- score tile: rows M0..M0+63, cols j0+wave*32 .. +32
    f32x4 sacc[4][2] = {};
    for (int k0 = 0; k0 < 256; k0 += 32) {
      half8 af[4], bf[2];
#pragma unroll
      for (int mt = 0; mt < 4; ++mt)
        af[mt] = *(const half8*)&QK16[(size_t)(M0 + mt*16 + c) * 512 + k0 + quad*8];
#pragma unroll
      for (int nt = 0; nt < 2; ++nt)
        bf[nt] = *(const half8*)&QK16[(size_t)(j0 + wave*32 + nt*16 + c) * 512 + 256 + k0 + quad*8];
#pragma unroll
      for (int mt = 0; mt < 4; ++mt)
#pragma unroll
        for (int nt = 0; nt < 2; ++nt)
          sacc[mt][nt] = __builtin_amdgcn_mfma_f32_16x16x32_f16(af[mt], bf[nt], sacc[mt][nt], 0, 0, 0);
    }

    __syncthreads();   // prior iteration's Ps reads complete
#pragma unroll
    for (int mt = 0; mt < 4; ++mt)
#pragma unroll
      for (int nt = 0; nt < 2; ++nt)
#pragma unroll
        for (int r = 0; r < 4; ++r) {
          const float p = __expf(sacc[mt][nt][r] * 0.0625f);
          psum[mt][r] += p;
          Ps[(mt*16 + quad*4 + r) * PSTRIDE + wave*32 + nt*16 + c] = (_Float16)p;
        }
    __syncthreads();

    // ---- PV: cacc += Ps(64x128) @ VT(dcols, j)^T
#pragma unroll
    for (int kk = 0; kk < 128; kk += 32) {
      half8 af[4], bf[4];
#pragma unroll
      for (int mt = 0; mt < 4; ++mt)
        af[mt] = *(const half8*)&Ps[(mt*16 + c) * PSTRIDE + kk + quad*8];
#pragma unroll
      for (int nt = 0; nt < 4; ++nt)
        bf[nt] = *(const half8*)&VT[(size_t)(wave*64 + nt*16 + c) * NSEQ + j0 + kk + quad*8];
#pragma unroll
      for (int mt = 0; mt < 4; ++mt)
#pragma unroll
        for (int nt = 0; nt < 4; ++nt)
          cacc[mt][nt] = __builtin_amdgcn_mfma_f32_16x16x32_f16(af[mt], bf[nt], cacc[mt][nt], 0, 0, 0);
    }
  }

  // ---- row-sum reduction across the 16 col-lanes, one atomic per row
#pragma unroll
  for (int mt = 0; mt < 4; ++mt)
#pragma unroll
    for (int r = 0; r < 4; ++r) {
      float v = psum[mt][r];
      v += __shfl_xor(v, 1);
      v += __shfl_xor(v, 2);
      v += __shfl_xor(v, 4);
      v += __shfl_xor(v, 8);
      if (c == 0) atomicAdd(&lsum[M0 + mt*16 + quad*4 + r], v);
    }

  // ---- cntx accumulate (split-K across JG groups), UNNORMALIZED
#pragma unroll
  for (int mt = 0; mt < 4; ++mt)
#pragma unroll
    for (int nt = 0; nt < 4; ++nt)
#pragma unroll
      for (int r = 0; r < 4; ++r)
        atomicAdd(&cntx[(size_t)(M0 + mt*16 + quad*4 + r) * D_MODEL + wave*64 + nt*16 + c],
                  cacc[mt][nt][r]);
}

// ---------------------------------------------------------------------------
// k3: normalize cntx in place by 1/lsum[row]. 2M elems, f32x4 per thread.
// Runs after fused_pv (lsum final). ~16 MB traffic, ~3 us.
// ---------------------------------------------------------------------------
__global__ __launch_bounds__(256) void scale_cntx_kernel(
    float* __restrict__ cntx, const float* __restrict__ lsum)
{
  const int g   = blockIdx.x * 256 + threadIdx.x;   // 0..524287, 4 floats each
  const int row = g >> 6;                           // 64 vec4 per 256-col row
  const float s = 1.0f / lsum[row];
  f32x4 v = ((f32x4*)cntx)[g];
  ((f32x4*)cntx)[g] = v * s;
}

// ---------------------------------------------------------------------------
// k4: recompute scores, normalize with final lsum, write attn ONCE.
// Wave tile 64x64, WG 128x128, grid (64,64). Pure write-bound: 268 MB.
// ---------------------------------------------------------------------------
__global__ __launch_bounds__(256) void attn_kernel(
    const _Float16* __restrict__ QK16, const float* __restrict__ lsum,
    float* __restrict__ attn)
{
  const int tid  = threadIdx.x;
  const int lane = tid & 63;
  const int wave = tid >> 6;
  const int c    = lane & 15;
  const int quad = lane >> 4;
  const int M0   = blockIdx.x * 128 + (wave >> 1) * 64;
  const int N0   = blockIdx.y * 128 + (wave & 1) * 64;

  float linv[4][4];
#pragma unroll
  for (int mt = 0; mt < 4; ++mt)
#pragma unroll
    for (int r = 0; r < 4; ++r)
      linv[mt][r] = 1.0f / lsum[M0 + mt*16 + quad*4 + r];

  f32x4 acc[4][4] = {};
  for (int k0 = 0; k0 < 256; k0 += 32) {
    half8 af[4], bf[4];
#pragma unroll
    for (int mt = 0; mt < 4; ++mt)
      af[mt] = *(const half8*)&QK16[(size_t)(M0 + mt*16 + c) * 512 + k0 + quad*8];
#pragma unroll
    for (int nt = 0; nt < 4; ++nt)
      bf[nt] = *(const half8*)&QK16[(size_t)(N0 + nt*16 + c) * 512 + 256 + k0 + quad*8];
#pragma unroll
    for (int mt = 0; mt < 4; ++mt)
#pragma unroll
      for (int nt = 0; nt < 4; ++nt)
        acc[mt][nt] = __builtin_amdgcn_mfma_f32_16x16x32_f16(af[mt], bf[nt], acc[mt][nt], 0, 0, 0);
  }

#pragma unroll
  for (int mt = 0; mt < 4; ++mt)
#pragma unroll
    for (int nt = 0; nt < 4; ++nt)
#pragma unroll
      for (int r = 0; r < 4; ++r)
        attn[(size_t)(M0 + mt*16 + quad*4 + r) * NSEQ + N0 + nt*16 + c] =
            __expf(acc[mt][nt][r] * 0.0625f) * linv[mt][r];
}

// ---------------------------------------------------------------------------
extern "C" void kernel_launch(void* const* d_in, const int* in_sizes, int n_in,
                              void* d_out, int out_size, void* d_ws, size_t ws_size,
                              hipStream_t stream)
{
  const float* x  = (const float*)d_in[0];
  const float* Wq = (const float*)d_in[1];
  const float* Wk = (const float*)d_in[2];
  const float* Wv = (const float*)d_in[3];

  float* cntx = (float*)d_out;                         // [8192 x 256]
  float* attn = cntx + (size_t)NSEQ * D_MODEL;         // [8192 x 8192]

  // ws layout: QK16 (8MB) | VT (4MB) | lsum (32KB)
  _Float16* QK16 = (_Float16*)d_ws;
  _Float16* VT   = QK16 + (size_t)NSEQ * 512;
  float*    lsum = (float*)(VT + (size_t)D_MODEL * NSEQ);

  hipMemsetAsync(cntx, 0, sizeof(float) * (size_t)NSEQ * D_MODEL, stream);
  hipMemsetAsync(lsum, 0, sizeof(float) * NSEQ, stream);

  qkv_kernel<<<dim3(64, 6), 256, 0, stream>>>(x, Wq, Wk, Wv, QK16, VT);
  fused_pv_kernel<<<dim3(NSEQ / 64, JG), 256, 0, stream>>>(QK16, VT, lsum, cntx);
  scale_cntx_kernel<<<dim3(2048), 256, 0, stream>>>(cntx, lsum);
  attn_kernel<<<dim3(64, 64), 256, 0, stream>>>(QK16, lsum, attn);
}